// Round 8
// baseline (188.244 us; speedup 1.0000x reference)
//
#include <hip/hip_runtime.h>
#include <cstdint>

#define TOK 16384
#define HD 2048
#define NE 64
#define HQ 512
#define KC 32                  // k per chunk
#define CHW 16                 // chunks per wave (512 k / 32)
#define ESCALE 1073741824.0f   // 2^30
#define STB 512                // selthr block size

// ---------------------------------------------------------------------------
// K1: router logits = hid @ rw^T (f32) + fused colsum partials.
// LDS-instruction-bound design: 8 tok x 8 exp per thread (LDS:FMA instr
// ratio 0.0625 -> ~98k LDS cyc/CU ~ 41us floor vs 295k/123us at 2x4).
// Block = 4 waves, tile 64 tok x 64 exp; INTRA-BLOCK K-SPLIT: wave w owns
// k in [w*512,(w+1)*512), each wave independent (private 32KB dbuf LDS, no
// barriers in main loop), partials reduced via LDS in fixed order at end
// (deterministic, no global partial buffers). Grid 256 = 1 block/CU.
// Swizzle slot=(q^(row>>3))&7: staging writes and compute reads both
// bank-balanced (writes 8 lanes x 8 groups = inherent floor; reads 8
// distinct bank-quads x 8-way broadcast).
// ---------------------------------------------------------------------------
__global__ __launch_bounds__(256, 1) void k_router(const float* __restrict__ hid,
                                                   const float* __restrict__ rw,
                                                   float* __restrict__ logits,
                                                   float* __restrict__ csP) {
  __shared__ __align__(16) float LA[4][2 * 64 * KC];  // 64 KB (per-wave 16KB dbuf)
  __shared__ __align__(16) float LB[4][2 * 64 * KC];  // 64 KB
  const int tid = threadIdx.x;
  const int lane = tid & 63;
  const int w = tid >> 6;
  const int tm = lane >> 3, tn = lane & 7;
  const int t0 = blockIdx.x * 64;
  const int kb = w * 512;                    // this wave's k-range base
  const float* ga = hid + (size_t)(t0 + lane) * HD + kb;  // lane stages A row `lane`
  const float* gb = rw + (size_t)lane * HD + kb;          // and B row `lane`
  float* Aw = LA[w];
  float* Bw = LB[w];
  // staging write offsets: lane writes row=lane, quad q at slot (q^(lane>>3))
  int woff[8];
#pragma unroll
  for (int q = 0; q < 8; ++q)
    woff[q] = lane * KC + (((q ^ (lane >> 3)) & 7) << 2);

  float acc[8][8];
#pragma unroll
  for (int i = 0; i < 8; ++i)
#pragma unroll
    for (int j = 0; j < 8; ++j) acc[i][j] = 0.f;

  float4 pa[8], pb[8];
#pragma unroll
  for (int q = 0; q < 8; ++q) {
    pa[q] = *(const float4*)(ga + q * 4);
    pb[q] = *(const float4*)(gb + q * 4);
  }

  for (int c = 0; c < CHW; ++c) {
    const int cb = (c & 1) * (64 * KC);
    // write staged chunk (bank-balanced: 8 distinct slots x 8 lanes each)
#pragma unroll
    for (int q = 0; q < 8; ++q) {
      *(float4*)(Aw + cb + woff[q]) = pa[q];
      *(float4*)(Bw + cb + woff[q]) = pb[q];
    }
    // prefetch next chunk (latency hidden under ~4k cyc of FMA below)
    if (c + 1 < CHW) {
#pragma unroll
      for (int q = 0; q < 8; ++q) {
        pa[q] = *(const float4*)(ga + (c + 1) * KC + q * 4);
        pb[q] = *(const float4*)(gb + (c + 1) * KC + q * 4);
      }
    }
    // colsum partial for this chunk (column reads, 2-way alias = free)
    {
      const int kk = lane & 31, half = lane >> 5;
      const int kq = kk >> 2, ks2 = kk & 3;
      float s = 0.f;
#pragma unroll
      for (int i = 0; i < 32; ++i) {
        const int row = half * 32 + i;
        s += Aw[cb + row * KC + (((kq ^ (row >> 3)) & 7) << 2) + ks2];
      }
      s += __shfl_down(s, 32);
      if (lane < 32) csP[(size_t)blockIdx.x * HD + kb + c * KC + lane] = s;
    }
    // compute: 8 quads x (16 b128 reads : 256 FMA)
#pragma unroll
    for (int q = 0; q < 8; ++q) {
      float4 bf[8];
#pragma unroll
      for (int j = 0; j < 8; ++j)
        bf[j] = *(const float4*)(Bw + cb + (tn * 8 + j) * KC + (((q ^ tn) & 7) << 2));
#pragma unroll
      for (int i = 0; i < 8; ++i) {
        const float4 af = *(const float4*)(Aw + cb + (tm * 8 + i) * KC + (((q ^ tm) & 7) << 2));
#pragma unroll
        for (int j = 0; j < 8; ++j) {
          acc[i][j] = fmaf(af.x, bf[j].x, acc[i][j]);
          acc[i][j] = fmaf(af.y, bf[j].y, acc[i][j]);
          acc[i][j] = fmaf(af.z, bf[j].z, acc[i][j]);
          acc[i][j] = fmaf(af.w, bf[j].w, acc[i][j]);
        }
      }
    }
  }
  // write this wave's 64x64 k-partial over its own LA region (4096 floats)
#pragma unroll
  for (int i = 0; i < 8; ++i) {
    *(float4*)(Aw + (tm * 8 + i) * 64 + tn * 8) =
        make_float4(acc[i][0], acc[i][1], acc[i][2], acc[i][3]);
    *(float4*)(Aw + (tm * 8 + i) * 64 + tn * 8 + 4) =
        make_float4(acc[i][4], acc[i][5], acc[i][6], acc[i][7]);
  }
  __syncthreads();
  // deterministic fixed-order 4-way reduce + coalesced store
  const int row = tid >> 2, c0 = (tid & 3) * 16;
#pragma unroll
  for (int q = 0; q < 4; ++q) {
    float4 s0 = *(const float4*)(LA[0] + row * 64 + c0 + q * 4);
    float4 s1 = *(const float4*)(LA[1] + row * 64 + c0 + q * 4);
    float4 s2 = *(const float4*)(LA[2] + row * 64 + c0 + q * 4);
    float4 s3 = *(const float4*)(LA[3] + row * 64 + c0 + q * 4);
    float4 r;
    r.x = ((s0.x + s1.x) + s2.x) + s3.x;
    r.y = ((s0.y + s1.y) + s2.y) + s3.y;
    r.z = ((s0.z + s1.z) + s2.z) + s3.z;
    r.w = ((s0.w + s1.w) + s2.w) + s3.w;
    *(float4*)(logits + (size_t)(t0 + row) * NE + c0 + q * 4) = r;
  }
}

// ---------------------------------------------------------------------------
// K1b: colsum[k] = sum over 256 blocks (fixed order, deterministic).
// ---------------------------------------------------------------------------
__global__ __launch_bounds__(256) void k_reduce_cs(const float* __restrict__ csP,
                                                   float* __restrict__ colsum) {
  __shared__ float rr[4][64];
  const int tid = threadIdx.x;
  const int k = blockIdx.x * 64 + (tid & 63);
  const int part = tid >> 6;
  float s = 0.f;
  for (int b = part * 64; b < part * 64 + 64; ++b)
    s += csP[(size_t)b * HD + k];
  rr[part][tid & 63] = s;
  __syncthreads();
  if (tid < 64)
    colsum[blockIdx.x * 64 + tid] = rr[0][tid] + rr[1][tid] + rr[2][tid] + rr[3][tid];
}

// ---------------------------------------------------------------------------
// K2a: h = relu(cap_w1 @ mean_h + b1), one block per output row.
// ---------------------------------------------------------------------------
__global__ __launch_bounds__(256) void k_cap1(const float* __restrict__ w1,
                                              const float* __restrict__ b1,
                                              const float* __restrict__ colsum,
                                              float* __restrict__ h) {
  const int row = blockIdx.x;
  const int tid = threadIdx.x;
  const float invB = 1.0f / 16384.0f;
  const float* wr = w1 + (size_t)row * HD;
  float4 a0 = *(const float4*)(wr + tid * 4);
  float4 a1 = *(const float4*)(wr + 1024 + tid * 4);
  float4 c0 = *(const float4*)(colsum + tid * 4);
  float4 c1 = *(const float4*)(colsum + 1024 + tid * 4);
  float s = a0.x * (c0.x * invB) + a0.y * (c0.y * invB) +
            a0.z * (c0.z * invB) + a0.w * (c0.w * invB) +
            a1.x * (c1.x * invB) + a1.y * (c1.y * invB) +
            a1.z * (c1.z * invB) + a1.w * (c1.w * invB);
#pragma unroll
  for (int off = 32; off; off >>= 1) s += __shfl_down(s, off);
  __shared__ float wsum[4];
  if ((tid & 63) == 0) wsum[tid >> 6] = s;
  __syncthreads();
  if (tid == 0) {
    float t = wsum[0] + wsum[1] + wsum[2] + wsum[3] + b1[row];
    h[row] = fmaxf(t, 0.f);
  }
}

// ---------------------------------------------------------------------------
// K2b+c fused: cap_logits = cap_w2 @ h + b2, softmax, clip, capacity.
// ---------------------------------------------------------------------------
__global__ __launch_bounds__(256) void k_caphead(const float* __restrict__ w2,
                                                 const float* __restrict__ b2,
                                                 const float* __restrict__ h,
                                                 int* __restrict__ cap) {
  __shared__ float clS[64];
  const int tid = threadIdx.x;
  const int e = tid >> 2, part = tid & 3;
  const float* wr = w2 + (size_t)e * HQ + part * 128;
  const float* hp = h + part * 128;
  float s = 0.f;
#pragma unroll
  for (int i = 0; i < 32; ++i) {
    float4 a = *(const float4*)(wr + i * 4);
    float4 hv = *(const float4*)(hp + i * 4);
    s += a.x * hv.x + a.y * hv.y + a.z * hv.z + a.w * hv.w;
  }
  s += __shfl_down(s, 1);
  s += __shfl_down(s, 2);
  if (part == 0) clS[e] = s + b2[e];
  __syncthreads();
  if (tid < 64) {
    float l = clS[tid];
    float m = l;
#pragma unroll
    for (int off = 1; off < 64; off <<= 1) m = fmaxf(m, __shfl_xor(m, off));
    float ex = expf(l - m);
    float sum = ex;
#pragma unroll
    for (int off = 1; off < 64; off <<= 1) sum += __shfl_xor(sum, off);
    float wgt = ex / sum;
    float cf = 1.25f + (wgt - 0.5f) * 1.0f;
    cf = fminf(fmaxf(cf, 1.0f), 2.0f);
    cap[tid] = (int)floorf(16384.0f * cf / 64.0f);
  }
}

// ---------------------------------------------------------------------------
// K3a: per-token softmax (reads logits [t][e] from d_out), writes probsT
// [e][t] via LDS transpose; entropy via int64 fixed-point atomic.
// ---------------------------------------------------------------------------
__global__ __launch_bounds__(256) void k_softmax(const float* __restrict__ logits,
                                                 float* __restrict__ probsT,
                                                 unsigned long long* __restrict__ ent) {
  __shared__ float tpT[64][65];
  __shared__ float sw[4];
  const int tid = threadIdx.x;
  const int lane = tid & 63;
  const int wv = tid >> 6;
  const int t0 = blockIdx.x * 64;
  const int tt = tid >> 2, q = tid & 3;
  const float* lr = logits + (size_t)(t0 + tt) * NE + q * 16;
  float4 v0 = *(const float4*)(lr);
  float4 v1 = *(const float4*)(lr + 4);
  float4 v2 = *(const float4*)(lr + 8);
  float4 v3 = *(const float4*)(lr + 12);
  float p[16] = {v0.x, v0.y, v0.z, v0.w, v1.x, v1.y, v1.z, v1.w,
                 v2.x, v2.y, v2.z, v2.w, v3.x, v3.y, v3.z, v3.w};
  float m = p[0];
#pragma unroll
  for (int i = 1; i < 16; ++i) m = fmaxf(m, p[i]);
  m = fmaxf(m, __shfl_xor(m, 1));
  m = fmaxf(m, __shfl_xor(m, 2));
  float s = 0.f;
#pragma unroll
  for (int i = 0; i < 16; ++i) { p[i] = expf(p[i] - m); s += p[i]; }
  s += __shfl_xor(s, 1);
  s += __shfl_xor(s, 2);
  const float inv = 1.0f / s;
  float el = 0.f;
#pragma unroll
  for (int i = 0; i < 16; ++i) {
    float pp = p[i] * inv;
    p[i] = pp;
    el += pp * logf(pp + 1e-8f);
  }
  el += __shfl_xor(el, 1);
  el += __shfl_xor(el, 2);
#pragma unroll
  for (int i = 0; i < 16; ++i) tpT[q * 16 + i][tt] = p[i];
  float ew = (q == 0) ? el : 0.f;
#pragma unroll
  for (int off = 4; off < 64; off <<= 1) ew += __shfl_xor(ew, off);
  if (lane == 0) sw[wv] = ew;
  __syncthreads();
  if (tid == 0) {
    float bt = sw[0] + sw[1] + sw[2] + sw[3];
    atomicAdd(ent, (unsigned long long)(long long)__float2ll_rn(bt * ESCALE));
  }
  const int er = tid >> 6, tl = tid & 63;
#pragma unroll
  for (int pass = 0; pass < 16; ++pass) {
    const int e = pass * 4 + er;
    probsT[(size_t)e * TOK + t0 + tl] = tpT[e][tl];
  }
}

// ---------------------------------------------------------------------------
// K3b: per-expert exact k-th largest prob: 3-pass radix select (2048-bin
// LDS hist, uint4 loads, parallel suffix scan), 512 thr, 1 block/expert.
// ---------------------------------------------------------------------------
__global__ __launch_bounds__(STB) void k_selthr(const float* __restrict__ probsT,
                                                const int* __restrict__ cap,
                                                unsigned* __restrict__ thrT,
                                                int* __restrict__ cutoff) {
  const int e = blockIdx.x, tid = threadIdx.x;
  const uint4* col4 = (const uint4*)(probsT + (size_t)e * TOK);
  const unsigned* col = (const unsigned*)(probsT + (size_t)e * TOK);
  __shared__ unsigned hist[2048];
  __shared__ int wsfx[STB];
  __shared__ unsigned sh_pref;
  __shared__ int sh_rem;
  __shared__ int sred[8], sgt[8], seq2[8];
  const int k = cap[e];
  unsigned prefix = 0, pmask = 0;
  int rem = k;
#pragma unroll
  for (int pass = 0; pass < 3; ++pass) {
    const int shift = (pass == 0) ? 21 : (pass == 1) ? 10 : 0;
    const int nb = (pass == 2) ? 1024 : 2048;
    const unsigned bmask = nb - 1;
    for (int i = tid; i < nb; i += STB) hist[i] = 0;
    __syncthreads();
    for (int it = 0; it < TOK / (4 * STB); ++it) {
      uint4 v = col4[it * STB + tid];
      if ((v.x & pmask) == prefix) atomicAdd(&hist[(v.x >> shift) & bmask], 1u);
      if ((v.y & pmask) == prefix) atomicAdd(&hist[(v.y >> shift) & bmask], 1u);
      if ((v.z & pmask) == prefix) atomicAdd(&hist[(v.z >> shift) & bmask], 1u);
      if ((v.w & pmask) == prefix) atomicAdd(&hist[(v.w >> shift) & bmask], 1u);
    }
    __syncthreads();
    const int cs = nb / STB;
    const int base = tid * cs;
    int s = 0;
    for (int m2 = 0; m2 < cs; ++m2) s += (int)hist[base + m2];
    wsfx[tid] = s;
    __syncthreads();
    for (int off = 1; off < STB; off <<= 1) {
      int v = (tid + off < STB) ? wsfx[tid + off] : 0;
      __syncthreads();
      wsfx[tid] += v;
      __syncthreads();
    }
    int r = (tid < STB - 1) ? wsfx[tid + 1] : 0;
    for (int m2 = cs - 1; m2 >= 0; --m2) {
      int rb = r + (int)hist[base + m2];
      if (rb >= rem && r < rem) {
        sh_pref = prefix | ((unsigned)(base + m2) << shift);
        sh_rem = rem - r;
      }
      r = rb;
    }
    __syncthreads();
    prefix = sh_pref;
    rem = sh_rem;
    pmask |= bmask << shift;
    __syncthreads();
  }
  const unsigned T = prefix;
  int lgt = 0, leq = 0;
  for (int it = 0; it < TOK / (4 * STB); ++it) {
    uint4 v = col4[it * STB + tid];
    lgt += (v.x > T) + (v.y > T) + (v.z > T) + (v.w > T);
    leq += (v.x == T) + (v.y == T) + (v.z == T) + (v.w == T);
  }
#pragma unroll
  for (int off = 32; off; off >>= 1) {
    lgt += __shfl_down(lgt, off);
    leq += __shfl_down(leq, off);
  }
  if ((tid & 63) == 0) { sgt[tid >> 6] = lgt; seq2[tid >> 6] = leq; }
  __syncthreads();
  int c_gt = 0, c_eq = 0;
#pragma unroll
  for (int i = 0; i < 8; ++i) { c_gt += sgt[i]; c_eq += seq2[i]; }
  const int n_allowed = k - c_gt;
  int cut;
  if (n_allowed <= 0) {
    cut = -1;
  } else if (c_eq <= n_allowed) {
    cut = 0x7fffffff;
  } else {
    int lo = 0, hi = TOK - 1;
    while (lo < hi) {
      const int mid = (lo + hi) >> 1;
      int c = 0;
      for (int i = tid; i <= mid; i += STB) c += (col[i] == T);
#pragma unroll
      for (int off = 32; off; off >>= 1) c += __shfl_down(c, off);
      __syncthreads();
      if ((tid & 63) == 0) sred[tid >> 6] = c;
      __syncthreads();
      int cnt = 0;
#pragma unroll
      for (int i = 0; i < 8; ++i) cnt += sred[i];
      if (cnt >= n_allowed) hi = mid; else lo = mid + 1;
    }
    cut = lo;
  }
  if (tid == 0) { thrT[e] = T; cutoff[e] = cut; }
}

// ---------------------------------------------------------------------------
// K3c: per-token selection + weight + entropy finalize.
// ---------------------------------------------------------------------------
__global__ __launch_bounds__(256) void k_final(const float* __restrict__ probsT,
                                               const unsigned* __restrict__ thrT,
                                               const int* __restrict__ cutoff,
                                               const unsigned long long* __restrict__ ent,
                                               float* __restrict__ out_sel,
                                               float* __restrict__ out_w,
                                               float* __restrict__ out_ent) {
  __shared__ float tp[64][65];
  __shared__ unsigned sT[64];
  __shared__ int sC[64];
  const int tid = threadIdx.x;
  const int t0 = blockIdx.x * 64;
  if (tid < 64) { sT[tid] = thrT[tid]; sC[tid] = cutoff[tid]; }
  const int er = tid >> 6, tl2 = tid & 63;
#pragma unroll
  for (int pass = 0; pass < 16; ++pass) {
    const int e = pass * 4 + er;
    tp[e][tl2] = probsT[(size_t)e * TOK + t0 + tl2];
  }
  __syncthreads();
  const int tl = tid >> 2, q = tid & 3;
  const int t_abs = t0 + tl;
  int best = -1;
  float bw = 0.f;
  for (int i = 15; i >= 0; --i) {
    const int e = q * 16 + i;
    const float p = tp[e][tl];
    const unsigned v = __float_as_uint(p);
    const unsigned T = sT[e];
    if (v > T || (v == T && t_abs <= sC[e])) { best = e; bw = p; break; }
  }
#pragma unroll
  for (int off = 1; off <= 2; off <<= 1) {
    const int b2 = __shfl_xor(best, off);
    const float w2 = __shfl_xor(bw, off);
    if (b2 > best) { best = b2; bw = w2; }
  }
  if (q == 0) {
    out_sel[t_abs] = (float)(best >= 0 ? best : 0);
    out_w[t_abs] = (best >= 0 ? bw : 0.0f);
  }
  if (blockIdx.x == 0 && tid == 0)
    out_ent[0] = -((float)(long long)ent[0] * (1.0f / ESCALE)) / 16384.0f;
}

// ---------------------------------------------------------------------------
extern "C" void kernel_launch(void* const* d_in, const int* in_sizes, int n_in,
                              void* d_out, int out_size, void* d_ws, size_t ws_size,
                              hipStream_t stream) {
  (void)in_sizes; (void)n_in; (void)out_size; (void)ws_size;
  const float* hid = (const float*)d_in[0];
  const float* rw  = (const float*)d_in[1];
  const float* w1  = (const float*)d_in[2];
  const float* b1  = (const float*)d_in[3];
  const float* w2  = (const float*)d_in[4];
  const float* b2  = (const float*)d_in[5];
  float* out = (float*)d_out;
  float* logits  = out;
  float* out_sel = out + (size_t)TOK * NE;
  float* out_w   = out_sel + TOK;
  float* out_ent = out_w + TOK;
  char* ws = (char*)d_ws;
  float*              colsum = (float*)(ws + 0);        // 2048 f32
  unsigned long long* ent    = (unsigned long long*)(ws + 8192);
  float*              h      = (float*)(ws + 8448);     // 512 f32
  int*                cap    = (int*)(ws + 10752);
  unsigned*           thr    = (unsigned*)(ws + 11008);
  int*                cut    = (int*)(ws + 11264);
  // region X (4 MiB): csP (256 blocks x 2048 f32 = 2 MB; K1 -> K1b) then
  // probsT (4 MiB; K3a -> K3b/K3c). Stream-ordered reuse, no overlap.
  float*              csP    = (float*)(ws + 16384);
  float*              probsT = (float*)(ws + 16384);

  hipMemsetAsync(ent, 0, 8, stream);
  hipLaunchKernelGGL(k_router, dim3(TOK / 64), dim3(256), 0, stream,
                     hid, rw, logits, csP);
  hipLaunchKernelGGL(k_reduce_cs, dim3(HD / 64), dim3(256), 0, stream, csP, colsum);
  hipLaunchKernelGGL(k_cap1, dim3(HQ), dim3(256), 0, stream, w1, b1, colsum, h);
  hipLaunchKernelGGL(k_caphead, dim3(1), dim3(256), 0, stream, w2, b2, h, cap);
  hipLaunchKernelGGL(k_softmax, dim3(TOK / 64), dim3(256), 0, stream,
                     logits, probsT, ent);
  hipLaunchKernelGGL(k_selthr, dim3(NE), dim3(STB), 0, stream, probsT, cap, thr, cut);
  hipLaunchKernelGGL(k_final, dim3(TOK / 64), dim3(256), 0, stream,
                     probsT, thr, cut, ent, out_sel, out_w, out_ent);
}